// Round 9
// baseline (92.288 us; speedup 1.0000x reference)
//
#include <hip/hip_runtime.h>
#include <hip/hip_bf16.h>
#include <cstddef>
#include <cstdint>

#define BATCH 131072
#define HOFF ((size_t)BATCH * 66)

typedef __attribute__((ext_vector_type(8))) short short8;
typedef __attribute__((ext_vector_type(4))) short short4v;
typedef __attribute__((ext_vector_type(4))) float f32x4;
typedef __attribute__((ext_vector_type(16))) float f32x16;

typedef const __attribute__((address_space(1))) unsigned int* gas_t;
typedef __attribute__((address_space(3))) unsigned int* las_t;

// d_ws (bf16 elems): fuse [128][104] | 4 GRU j2-units ([6 gate-part][32 r][136]=26112)
//                    | 10 head units ([32][136]=4352)
#define WS_GRU    13312
#define WS_GUNIT  26112
#define WS_HEAD   117760            // 13312 + 4*26112
#define WS_ELEMS  161280            // + 10*4352

// smem (shorts): fuse [0,13312) | G: 2 j2-units [13312,65536) | strips 8x1280 [65536,75776)
#define G_BASE    13312
#define STR_BASE  65536

#define MFMA32(a,b,c) __builtin_amdgcn_mfma_f32_32x32x16_bf16((a),(b),(c),0,0,0)

__device__ __forceinline__ short f2bf(float x) {
    __hip_bfloat16 b = __float2bfloat16(x);
    return __builtin_bit_cast(short, b);
}
__device__ __forceinline__ float bf2f(short s) {
    unsigned u = ((unsigned)(unsigned short)s) << 16;
    return __builtin_bit_cast(float, u);
}
__device__ __forceinline__ float fsigmoid(float x) { return __builtin_amdgcn_rcpf(1.0f + __expf(-x)); }
__device__ __forceinline__ float ftanh(float x)    { return 1.0f - 2.0f * __builtin_amdgcn_rcpf(1.0f + __expf(2.0f * x)); }

__device__ __forceinline__ short8 packbf(f32x4 a, f32x4 b) {
    short8 r;
    r[0]=f2bf(a[0]); r[1]=f2bf(a[1]); r[2]=f2bf(a[2]); r[3]=f2bf(a[3]);
    r[4]=f2bf(b[0]); r[5]=f2bf(b[1]); r[6]=f2bf(b[2]); r[7]=f2bf(b[3]);
    return r;
}

// async global->LDS: linear dest, 16B/lane; 512-thread chunking, tail guards wave-uniform
// (1664: t<128; 6528: t<384; 5440: t<320)
template<int NCH>
__device__ __forceinline__ void stage_lds(const short* __restrict__ src, short* dst, int t) {
    constexpr int NP = (NCH + 511) / 512;
    #pragma unroll
    for (int k = 0; k < NP; ++k) {
        int c = t + 512 * k;
        if ((NCH % 512 == 0) || c < NCH)
            __builtin_amdgcn_global_load_lds((gas_t)(const void*)(src + (size_t)c * 8),
                                             (las_t)(void*)(dst + (size_t)c * 8), 16, 0, 0);
    }
}

// ---------------- prep: f32 weights -> bf16 units in d_ws ----------------
extern "C" __global__ void prep_weights(const float* __restrict__ fuse_W,
                                        const float* __restrict__ W_ih, const float* __restrict__ W_hh,
                                        const float* __restrict__ ns_W1, const float* __restrict__ ns_W2,
                                        const float* __restrict__ rw_W1, const float* __restrict__ dn_W1,
                                        short* __restrict__ ws) {
    int i = blockIdx.x * 256 + threadIdx.x;
    if (i >= WS_ELEMS) return;
    float v = 0.f;
    if (i < WS_GRU) {                       // fuse: [128][104], K padded 80->104
        int j = i / 104, k = i % 104;
        if (k < 80) v = fuse_W[j*80 + k];
    } else if (i < WS_HEAD) {               // GRU j2-units: [gp = g*2+p][32 r][136]
        int rel = i - WS_GRU;
        int u2 = rel / WS_GUNIT, e = rel % WS_GUNIT;
        int rb = e / 136, k = e % 136;
        if (k < 128) {
            int gp = rb >> 5, r = rb & 31;
            int g = gp >> 1, p = gp & 1;
            const float* W = p ? W_hh : W_ih;
            v = W[(size_t)(g*128 + u2*32 + r)*128 + k];
        }
    } else {                                // head units [32][136]: 0-3 ns_W1, 4-5 ns_W2, 6-7 rw_W1, 8-9 dn_W1
        int rel = i - WS_HEAD;
        int h = rel / 4352, e = rel % 4352;
        int r = e / 136, k = e % 136;
        if (k < 128) {
            const float* W; int rb;
            if (h < 4)      { W = ns_W1; rb = h*32; }
            else if (h < 6) { W = ns_W2; rb = (h-4)*32; }
            else if (h < 8) { W = rw_W1; rb = (h-6)*32; }
            else            { W = dn_W1; rb = (h-8)*32; }
            v = W[(size_t)(rb + r)*128 + k];
        }
    }
    ws[i] = f2bf(v);
}

// GRU 32-col group J2 using j2-unit slot U: r,z fused K=256; n split; elementwise -> strip
#define GRU_J2(U, J2) do {                                                                 \
    const int ub = G_BASE + (U)*WS_GUNIT;                                                  \
    const int cb = (J2)*32 + ln;                                                           \
    const float br  = b_ih[cb]       + b_hh[cb];                                           \
    const float bz  = b_ih[128 + cb] + b_hh[128 + cb];                                     \
    const float bin = b_ih[256 + cb];                                                      \
    const float bhn = b_hh[256 + cb];                                                      \
    f32x16 ar = zz16, az = zz16, ain = zz16, ahn = zz16;                                   \
    _Pragma("unroll") for (int kf = 0; kf < 8; ++kf) {                                     \
        const int ko = kf*16 + hb8;                                                        \
        short8 B0 = *(const short8*)&smem[ub + (0*32 + ln)*136 + ko];                      \
        ar  = MFMA32(xa[kf], B0, ar);                                                      \
        short8 B1 = *(const short8*)&smem[ub + (1*32 + ln)*136 + ko];                      \
        ar  = MFMA32(ha[kf], B1, ar);                                                      \
        short8 B2 = *(const short8*)&smem[ub + (2*32 + ln)*136 + ko];                      \
        az  = MFMA32(xa[kf], B2, az);                                                      \
        short8 B3 = *(const short8*)&smem[ub + (3*32 + ln)*136 + ko];                      \
        az  = MFMA32(ha[kf], B3, az);                                                      \
        short8 B4 = *(const short8*)&smem[ub + (4*32 + ln)*136 + ko];                      \
        ain = MFMA32(xa[kf], B4, ain);                                                     \
        short8 B5 = *(const short8*)&smem[ub + (5*32 + ln)*136 + ko];                      \
        ahn = MFMA32(ha[kf], B5, ahn);                                                     \
    }                                                                                      \
    _Pragma("unroll") for (int p = 0; p < 8; ++p) {                                        \
        unsigned hp = h0d[J2][p];                                                          \
        _Pragma("unroll") for (int q = 0; q < 2; ++q) {                                    \
            const int reg = 2*p + q;                                                       \
            float h0v = bf2f((short)(q ? (hp >> 16) : (hp & 0xffffu)));                    \
            float rg = fsigmoid(ar[reg] + br);                                             \
            float zg = fsigmoid(az[reg] + bz);                                             \
            float ng = ftanh(ain[reg] + bin + rg*(ahn[reg] + bhn));                        \
            S[((reg&3) + 8*(reg>>2) + hr4)*40 + ln] = f2bf((1.f - zg)*ng + zg*h0v);        \
        }                                                                                  \
    }                                                                                      \
} while (0)

// head GEMM: one 32-col group from head unit HU, result -> strip
#define HEAD32(FRAG, BIASEXPR, HU, RELU) do {                                              \
    f32x16 a = zz16;                                                                       \
    _Pragma("unroll") for (int kf = 0; kf < 8; ++kf) {                                     \
        short8 B = *(const short8*)&smem[G_BASE + (HU)*4352 + ln*136 + kf*16 + hb8];       \
        a = MFMA32((FRAG)[kf], B, a);                                                      \
    }                                                                                      \
    const float bb = (BIASEXPR);                                                           \
    _Pragma("unroll") for (int reg = 0; reg < 16; ++reg) {                                 \
        float v = a[reg] + bb;                                                             \
        if (RELU) v = fmaxf(v, 0.f);                                                       \
        S[((reg&3) + 8*(reg>>2) + hr4)*40 + ln] = f2bf(v);                                 \
    }                                                                                      \
} while (0)

// ---------------- main fused kernel: 512 threads (8 waves x 32 rows), grid 512 ----------------
extern "C" __global__ __launch_bounds__(512, 1)
void gru_mfma(const float* __restrict__ z_t, const int* __restrict__ action,
              const float* __restrict__ hidden, const float* __restrict__ embed,
              const float* __restrict__ fuse_b,
              const float* __restrict__ b_ih, const float* __restrict__ b_hh,
              const float* __restrict__ ns_b1, const float* __restrict__ ns_b2,
              const float* __restrict__ rw_b1, const float* __restrict__ rw_W2, const float* __restrict__ rw_b2,
              const float* __restrict__ dn_b1, const float* __restrict__ dn_W2, const float* __restrict__ dn_b2,
              const short* __restrict__ ws, float* out)
{
    __shared__ __align__(16) short smem[75776];   // 151.5 KB -> 1 block/CU

    const int t    = threadIdx.x;
    const int lane = t & 63;
    const int w    = t >> 6;
    const int ln   = lane & 31;                   // A row / B col / D col
    const int hb8  = (lane >> 5) * 8;             // k sub-offset
    const int hr4  = (lane >> 5) * 4;             // D row sub-offset
    const int R    = blockIdx.x * 256 + w * 32;   // wave's first batch row
    short* const S = &smem[STR_BASE + w * 1280];  // per-wave strip [32][40]

    const f32x16 zz16 = {0,0,0,0,0,0,0,0,0,0,0,0,0,0,0,0};

    auto store_hnew = [&](int j2) {
        #pragma unroll
        for (int v = 0; v < 4; ++v) {
            int idx = v*64 + lane;
            int r = idx >> 3, c = (idx & 7) * 4;
            short4v s = *(const short4v*)&S[r*40 + c];
            f32x4 f = { bf2f(s[0]), bf2f(s[1]), bf2f(s[2]), bf2f(s[3]) };
            *(f32x4*)&out[HOFF + (size_t)(R + r)*128 + j2*32 + c] = f;
        }
    };
    auto store_z = [&](int q) {
        #pragma unroll
        for (int v = 0; v < 4; ++v) {
            int idx = v*64 + lane;
            int r = idx >> 3, c = (idx & 7) * 4;
            short4v s = *(const short4v*)&S[r*40 + c];
            f32x4 f = { bf2f(s[0]), bf2f(s[1]), bf2f(s[2]), bf2f(s[3]) };
            *(f32x4*)&out[(size_t)(R + r)*64 + q*32 + c] = f;
        }
    };
    auto hpartial = [&](const float* W2, float acc) -> float {
        int rr = lane & 31;
        #pragma unroll
        for (int kk = 0; kk < 32; kk += 8) {
            short8 s = *(const short8*)&S[rr*40 + kk];
            f32x4 w0 = *(const f32x4*)&W2[kk];
            f32x4 w1 = *(const f32x4*)&W2[kk+4];
            acc += bf2f(s[0])*w0[0] + bf2f(s[1])*w0[1] + bf2f(s[2])*w0[2] + bf2f(s[3])*w0[3]
                 + bf2f(s[4])*w1[0] + bf2f(s[5])*w1[1] + bf2f(s[6])*w1[2] + bf2f(s[7])*w1[3];
        }
        return acc;
    };

    // ---- issue superphase-0 staging: fuse + GRU j2-units {0,1} ----
    stage_lds<1664>(ws, &smem[0], t);
    stage_lds<6528>(ws + WS_GRU, &smem[G_BASE], t);

    // ---- A-fragments direct from global (row = R + ln), f32 -> bf16 ----
    short8 fa[5];          // fused input K=80 (z_t 0..63 | emb 64..79)
    short8 ha[8];          // h0 K=128
    {
        const int row = R + ln;
        #pragma unroll
        for (int kf = 0; kf < 4; ++kf) {
            f32x4 p0 = *(const f32x4*)&z_t[(size_t)row*64 + kf*16 + hb8];
            f32x4 p1 = *(const f32x4*)&z_t[(size_t)row*64 + kf*16 + hb8 + 4];
            fa[kf] = packbf(p0, p1);
        }
        int a = action[row];
        f32x4 e0 = *(const f32x4*)&embed[a*16 + hb8];
        f32x4 e1 = *(const f32x4*)&embed[a*16 + hb8 + 4];
        fa[4] = packbf(e0, e1);
        #pragma unroll
        for (int kf = 0; kf < 8; ++kf) {
            f32x4 p0 = *(const f32x4*)&hidden[(size_t)row*128 + kf*16 + hb8];
            f32x4 p1 = *(const f32x4*)&hidden[(size_t)row*128 + kf*16 + hb8 + 4];
            ha[kf] = packbf(p0, p1);
        }
    }

    // ---- h0 in D layout via strip transposes (wave-private, pre-barrier) ----
    unsigned h0d[4][8];
    #pragma unroll
    for (int n = 0; n < 4; ++n) {
        *(short8*)&S[ln*40 + hb8]      = ha[2*n];
        *(short8*)&S[ln*40 + 16 + hb8] = ha[2*n+1];
        #pragma unroll
        for (int p = 0; p < 8; ++p) {
            const int r0 = 2*p, r1 = 2*p + 1;
            unsigned a = (unsigned short)S[((r0&3) + 8*(r0>>2) + hr4)*40 + ln];
            unsigned b = (unsigned short)S[((r1&3) + 8*(r1>>2) + hr4)*40 + ln];
            h0d[n][p] = a | (b << 16);
        }
    }
    __syncthreads();                       // B1: fuse + GRU sp0 resident

    // ---- fuse: x = relu(F @ fuse_W^T + b); 4 col-tiles; xa frags from strip ----
    short8 xa[8];
    #pragma unroll
    for (int n = 0; n < 4; ++n) {
        f32x16 a = zz16;
        #pragma unroll
        for (int kf = 0; kf < 5; ++kf) {
            short8 B = *(const short8*)&smem[(n*32 + ln)*104 + kf*16 + hb8];
            a = MFMA32(fa[kf], B, a);
        }
        float fb = fuse_b[n*32 + ln];
        #pragma unroll
        for (int reg = 0; reg < 16; ++reg)
            S[((reg&3) + 8*(reg>>2) + hr4)*40 + ln] = f2bf(fmaxf(a[reg] + fb, 0.f));
        xa[2*n]   = *(const short8*)&S[ln*40 + hb8];
        xa[2*n+1] = *(const short8*)&S[ln*40 + 16 + hb8];
    }

    // ---- GRU superphase 0: j2 = 0,1 ----
    short8 hfa[8];
    GRU_J2(0, 0);
    hfa[0] = *(const short8*)&S[ln*40 + hb8];
    hfa[1] = *(const short8*)&S[ln*40 + 16 + hb8];
    store_hnew(0);
    GRU_J2(1, 1);
    hfa[2] = *(const short8*)&S[ln*40 + hb8];
    hfa[3] = *(const short8*)&S[ln*40 + 16 + hb8];
    store_hnew(1);

    __syncthreads();                       // B2: done reading GRU sp0
    stage_lds<6528>(ws + WS_GRU + 2*WS_GUNIT, &smem[G_BASE], t);
    __syncthreads();                       // B3: sp1 resident

    // ---- GRU superphase 1: j2 = 2,3 ----
    GRU_J2(0, 2);
    hfa[4] = *(const short8*)&S[ln*40 + hb8];
    hfa[5] = *(const short8*)&S[ln*40 + 16 + hb8];
    store_hnew(2);
    GRU_J2(1, 3);
    hfa[6] = *(const short8*)&S[ln*40 + hb8];
    hfa[7] = *(const short8*)&S[ln*40 + 16 + hb8];
    store_hnew(3);

    __syncthreads();                       // B4: done reading GRU sp1
    stage_lds<5440>(ws + WS_HEAD, &smem[G_BASE], t);   // all 10 head units
    __syncthreads();                       // B5: heads resident

    // ---- heads: barrier-free ----
    short8 ta[8];
    HEAD32(hfa, ns_b1[ln],      0, true);
    ta[0] = *(const short8*)&S[ln*40 + hb8];
    ta[1] = *(const short8*)&S[ln*40 + 16 + hb8];
    HEAD32(hfa, ns_b1[32 + ln], 1, true);
    ta[2] = *(const short8*)&S[ln*40 + hb8];
    ta[3] = *(const short8*)&S[ln*40 + 16 + hb8];
    HEAD32(hfa, ns_b1[64 + ln], 2, true);
    ta[4] = *(const short8*)&S[ln*40 + hb8];
    ta[5] = *(const short8*)&S[ln*40 + 16 + hb8];
    HEAD32(hfa, ns_b1[96 + ln], 3, true);
    ta[6] = *(const short8*)&S[ln*40 + hb8];
    ta[7] = *(const short8*)&S[ln*40 + 16 + hb8];

    HEAD32(ta, ns_b2[ln],      4, false); store_z(0);
    HEAD32(ta, ns_b2[32 + ln], 5, false); store_z(1);

    float racc = rw_b2[0];
    HEAD32(hfa, rw_b1[ln],      6, true); racc = hpartial(rw_W2, racc);
    HEAD32(hfa, rw_b1[32 + ln], 7, true); racc = hpartial(rw_W2 + 32, racc);
    if (lane < 32) out[(size_t)BATCH*64 + R + ln] = racc;

    float dacc = dn_b2[0];
    HEAD32(hfa, dn_b1[ln],      8, true); dacc = hpartial(dn_W2, dacc);
    HEAD32(hfa, dn_b1[32 + ln], 9, true); dacc = hpartial(dn_W2 + 32, dacc);
    if (lane < 32) out[(size_t)BATCH*65 + R + ln] = dacc;
}

extern "C" void kernel_launch(void* const* d_in, const int* in_sizes, int n_in,
                              void* d_out, int out_size, void* d_ws, size_t ws_size,
                              hipStream_t stream) {
    const float* z_t    = (const float*)d_in[0];
    const int*   action = (const int*)  d_in[1];
    const float* hidden = (const float*)d_in[2];
    const float* embed  = (const float*)d_in[3];
    const float* fuse_W = (const float*)d_in[4];
    const float* fuse_b = (const float*)d_in[5];
    const float* W_ih   = (const float*)d_in[6];
    const float* W_hh   = (const float*)d_in[7];
    const float* b_ih   = (const float*)d_in[8];
    const float* b_hh   = (const float*)d_in[9];
    const float* ns_W1  = (const float*)d_in[10];
    const float* ns_b1  = (const float*)d_in[11];
    const float* ns_W2  = (const float*)d_in[12];
    const float* ns_b2  = (const float*)d_in[13];
    const float* rw_W1  = (const float*)d_in[14];
    const float* rw_b1  = (const float*)d_in[15];
    const float* rw_W2  = (const float*)d_in[16];
    const float* rw_b2  = (const float*)d_in[17];
    const float* dn_W1  = (const float*)d_in[18];
    const float* dn_b1  = (const float*)d_in[19];
    const float* dn_W2  = (const float*)d_in[20];
    const float* dn_b2  = (const float*)d_in[21];
    float* out = (float*)d_out;
    short* ws  = (short*)d_ws;

    hipLaunchKernelGGL(prep_weights, dim3((WS_ELEMS + 255) / 256), dim3(256), 0, stream,
                       fuse_W, W_ih, W_hh, ns_W1, ns_W2, rw_W1, dn_W1, ws);

    hipLaunchKernelGGL(gru_mfma, dim3(BATCH / 256), dim3(512), 0, stream,
                       z_t, action, hidden, embed,
                       fuse_b, b_ih, b_hh, ns_b1, ns_b2,
                       rw_b1, rw_W2, rw_b2, dn_b1, dn_W2, dn_b2,
                       ws, out);
}

// Round 10
// 78.340 us; speedup vs baseline: 1.1780x; 1.1780x over previous
//
#include <hip/hip_runtime.h>
#include <hip/hip_bf16.h>
#include <cstddef>
#include <cstdint>

#define BATCH 131072
#define HOFF ((size_t)BATCH * 66)

typedef __attribute__((ext_vector_type(8))) short short8;
typedef __attribute__((ext_vector_type(4))) short short4v;
typedef __attribute__((ext_vector_type(4))) float f32x4;
typedef __attribute__((ext_vector_type(16))) float f32x16;

typedef const __attribute__((address_space(1))) unsigned int* gas_t;
typedef __attribute__((address_space(3))) unsigned int* las_t;

// d_ws (bf16 elems): fuse [128][104] | 4 GRU j2-units ([6 gate-part][32 r][136]=26112)
//                    | 10 head units ([32][136]=4352)
#define WS_GRU    13312
#define WS_GUNIT  26112
#define WS_HEAD   117760            // 13312 + 4*26112
#define WS_ELEMS  161280            // + 10*4352

// smem (shorts): fuse [0,13312) | G: 2 j2-units [13312,65536) | strips 8x1280 [65536,75776)
#define G_BASE    13312
#define STR_BASE  65536

#define MFMA32(a,b,c) __builtin_amdgcn_mfma_f32_32x32x16_bf16((a),(b),(c),0,0,0)

__device__ __forceinline__ short f2bf(float x) {
    __hip_bfloat16 b = __float2bfloat16(x);
    return __builtin_bit_cast(short, b);
}
__device__ __forceinline__ float bf2f(short s) {
    unsigned u = ((unsigned)(unsigned short)s) << 16;
    return __builtin_bit_cast(float, u);
}
__device__ __forceinline__ float fsigmoid(float x) { return __builtin_amdgcn_rcpf(1.0f + __expf(-x)); }
__device__ __forceinline__ float ftanh(float x)    { return 1.0f - 2.0f * __builtin_amdgcn_rcpf(1.0f + __expf(2.0f * x)); }

__device__ __forceinline__ short8 packbf(f32x4 a, f32x4 b) {
    short8 r;
    r[0]=f2bf(a[0]); r[1]=f2bf(a[1]); r[2]=f2bf(a[2]); r[3]=f2bf(a[3]);
    r[4]=f2bf(b[0]); r[5]=f2bf(b[1]); r[6]=f2bf(b[2]); r[7]=f2bf(b[3]);
    return r;
}

// async global->LDS: linear dest, 16B/lane; 512-thread chunking, tail guards wave-uniform
template<int NCH>
__device__ __forceinline__ void stage_lds(const short* __restrict__ src, short* dst, int t) {
    constexpr int NP = (NCH + 511) / 512;
    #pragma unroll
    for (int k = 0; k < NP; ++k) {
        int c = t + 512 * k;
        if ((NCH % 512 == 0) || c < NCH)
            __builtin_amdgcn_global_load_lds((gas_t)(const void*)(src + (size_t)c * 8),
                                             (las_t)(void*)(dst + (size_t)c * 8), 16, 0, 0);
    }
}

// ---------------- prep: f32 weights -> bf16 units in d_ws (unchanged from R9) ----------------
extern "C" __global__ void prep_weights(const float* __restrict__ fuse_W,
                                        const float* __restrict__ W_ih, const float* __restrict__ W_hh,
                                        const float* __restrict__ ns_W1, const float* __restrict__ ns_W2,
                                        const float* __restrict__ rw_W1, const float* __restrict__ dn_W1,
                                        short* __restrict__ ws) {
    int i = blockIdx.x * 256 + threadIdx.x;
    if (i >= WS_ELEMS) return;
    float v = 0.f;
    if (i < WS_GRU) {                       // fuse: [128][104], K padded 80->104
        int j = i / 104, k = i % 104;
        if (k < 80) v = fuse_W[j*80 + k];
    } else if (i < WS_HEAD) {               // GRU j2-units: [gp = g*2+p][32 r][136]
        int rel = i - WS_GRU;
        int u2 = rel / WS_GUNIT, e = rel % WS_GUNIT;
        int rb = e / 136, k = e % 136;
        if (k < 128) {
            int gp = rb >> 5, r = rb & 31;
            int g = gp >> 1, p = gp & 1;
            const float* W = p ? W_hh : W_ih;
            v = W[(size_t)(g*128 + u2*32 + r)*128 + k];
        }
    } else {                                // head units [32][136]: 0-3 ns_W1, 4-5 ns_W2, 6-7 rw_W1, 8-9 dn_W1
        int rel = i - WS_HEAD;
        int h = rel / 4352, e = rel % 4352;
        int r = e / 136, k = e % 136;
        if (k < 128) {
            const float* W; int rb;
            if (h < 4)      { W = ns_W1; rb = h*32; }
            else if (h < 6) { W = ns_W2; rb = (h-4)*32; }
            else if (h < 8) { W = rw_W1; rb = (h-6)*32; }
            else            { W = dn_W1; rb = (h-8)*32; }
            v = W[(size_t)(rb + r)*128 + k];
        }
    }
    ws[i] = f2bf(v);
}

// GRU 32-col group J2 using j2-unit slot U. Sequential gates: only 2 f32x16 live.
// Deferred h0 transpose: 8-reg slice extracted here, not held globally.
#define GRU_J2(U, J2) do {                                                                 \
    const int ub = G_BASE + (U)*WS_GUNIT;                                                  \
    const int cb = (J2)*32 + ln;                                                           \
    /* h0 D-layout slice for this group via strip transpose */                             \
    *(short8*)&S[ln*40 + hb8]      = ha[2*(J2)];                                           \
    *(short8*)&S[ln*40 + 16 + hb8] = ha[2*(J2)+1];                                         \
    unsigned h0p[8];                                                                       \
    _Pragma("unroll") for (int p = 0; p < 8; ++p) {                                        \
        const int r0 = 2*p, r1 = 2*p + 1;                                                  \
        unsigned a = (unsigned short)S[((r0&3) + 8*(r0>>2) + hr4)*40 + ln];                \
        unsigned b = (unsigned short)S[((r1&3) + 8*(r1>>2) + hr4)*40 + ln];                \
        h0p[p] = a | (b << 16);                                                            \
    }                                                                                      \
    const float br  = b_ih[cb]       + b_hh[cb];                                           \
    const float bz  = b_ih[128 + cb] + b_hh[128 + cb];                                     \
    const float bin = b_ih[256 + cb];                                                      \
    const float bhn = b_hh[256 + cb];                                                      \
    f32x16 acc, tmp;                                                                       \
    /* r gate: K=256 fused */                                                              \
    acc = zz16;                                                                            \
    _Pragma("unroll") for (int kf = 0; kf < 8; ++kf) {                                     \
        const int ko = kf*16 + hb8;                                                        \
        short8 B0 = *(const short8*)&smem[ub + (0*32 + ln)*136 + ko];                      \
        acc = MFMA32(xa[kf], B0, acc);                                                     \
        short8 B1 = *(const short8*)&smem[ub + (1*32 + ln)*136 + ko];                      \
        acc = MFMA32(ha[kf], B1, acc);                                                     \
    }                                                                                      \
    _Pragma("unroll") for (int reg = 0; reg < 16; ++reg)                                   \
        tmp[reg] = fsigmoid(acc[reg] + br);                                                \
    /* ahn: t = rg*(ahn+bhn) */                                                            \
    acc = zz16;                                                                            \
    _Pragma("unroll") for (int kf = 0; kf < 8; ++kf) {                                     \
        short8 B5 = *(const short8*)&smem[ub + (5*32 + ln)*136 + kf*16 + hb8];             \
        acc = MFMA32(ha[kf], B5, acc);                                                     \
    }                                                                                      \
    _Pragma("unroll") for (int reg = 0; reg < 16; ++reg)                                   \
        tmp[reg] = tmp[reg] * (acc[reg] + bhn);                                            \
    /* ain: ng = tanh(ain+bin+t) */                                                        \
    acc = zz16;                                                                            \
    _Pragma("unroll") for (int kf = 0; kf < 8; ++kf) {                                     \
        short8 B4 = *(const short8*)&smem[ub + (4*32 + ln)*136 + kf*16 + hb8];             \
        acc = MFMA32(xa[kf], B4, acc);                                                     \
    }                                                                                      \
    _Pragma("unroll") for (int reg = 0; reg < 16; ++reg)                                   \
        tmp[reg] = ftanh(acc[reg] + bin + tmp[reg]);                                       \
    /* z gate: K=256 fused; then h_new -> strip */                                         \
    acc = zz16;                                                                            \
    _Pragma("unroll") for (int kf = 0; kf < 8; ++kf) {                                     \
        const int ko = kf*16 + hb8;                                                        \
        short8 B2 = *(const short8*)&smem[ub + (2*32 + ln)*136 + ko];                      \
        acc = MFMA32(xa[kf], B2, acc);                                                     \
        short8 B3 = *(const short8*)&smem[ub + (3*32 + ln)*136 + ko];                      \
        acc = MFMA32(ha[kf], B3, acc);                                                     \
    }                                                                                      \
    _Pragma("unroll") for (int p = 0; p < 8; ++p) {                                        \
        unsigned hp = h0p[p];                                                              \
        _Pragma("unroll") for (int q = 0; q < 2; ++q) {                                    \
            const int reg = 2*p + q;                                                       \
            float h0v = bf2f((short)(q ? (hp >> 16) : (hp & 0xffffu)));                    \
            float zg = fsigmoid(acc[reg] + bz);                                            \
            S[((reg&3) + 8*(reg>>2) + hr4)*40 + ln] = f2bf((1.f - zg)*tmp[reg] + zg*h0v);  \
        }                                                                                  \
    }                                                                                      \
} while (0)

// head GEMM: one 32-col group from head unit HU, result -> strip
#define HEAD32(FRAG, BIASEXPR, HU, RELU) do {                                              \
    f32x16 a = zz16;                                                                       \
    _Pragma("unroll") for (int kf = 0; kf < 8; ++kf) {                                     \
        short8 B = *(const short8*)&smem[G_BASE + (HU)*4352 + ln*136 + kf*16 + hb8];       \
        a = MFMA32((FRAG)[kf], B, a);                                                      \
    }                                                                                      \
    const float bb = (BIASEXPR);                                                           \
    _Pragma("unroll") for (int reg = 0; reg < 16; ++reg) {                                 \
        float v = a[reg] + bb;                                                             \
        if (RELU) v = fmaxf(v, 0.f);                                                       \
        S[((reg&3) + 8*(reg>>2) + hr4)*40 + ln] = f2bf(v);                                 \
    }                                                                                      \
} while (0)

// ---------------- main fused kernel: 512 threads (8 waves x 32 rows), grid 512 ----------------
extern "C" __global__ __launch_bounds__(512, 1)
void gru_mfma(const float* __restrict__ z_t, const int* __restrict__ action,
              const float* __restrict__ hidden, const float* __restrict__ embed,
              const float* __restrict__ fuse_b,
              const float* __restrict__ b_ih, const float* __restrict__ b_hh,
              const float* __restrict__ ns_b1, const float* __restrict__ ns_b2,
              const float* __restrict__ rw_b1, const float* __restrict__ rw_W2, const float* __restrict__ rw_b2,
              const float* __restrict__ dn_b1, const float* __restrict__ dn_W2, const float* __restrict__ dn_b2,
              const short* __restrict__ ws, float* out)
{
    __shared__ __align__(16) short smem[75776];   // 151.5 KB -> 1 block/CU

    const int t    = threadIdx.x;
    const int lane = t & 63;
    const int w    = t >> 6;
    const int ln   = lane & 31;                   // A row / B col / D col
    const int hb8  = (lane >> 5) * 8;             // k sub-offset
    const int hr4  = (lane >> 5) * 4;             // D row sub-offset
    const int R    = blockIdx.x * 256 + w * 32;   // wave's first batch row
    short* const S = &smem[STR_BASE + w * 1280];  // per-wave strip [32][40]

    const f32x16 zz16 = {0,0,0,0,0,0,0,0,0,0,0,0,0,0,0,0};

    auto store_hnew = [&](int j2) {
        #pragma unroll
        for (int v = 0; v < 4; ++v) {
            int idx = v*64 + lane;
            int r = idx >> 3, c = (idx & 7) * 4;
            short4v s = *(const short4v*)&S[r*40 + c];
            f32x4 f = { bf2f(s[0]), bf2f(s[1]), bf2f(s[2]), bf2f(s[3]) };
            *(f32x4*)&out[HOFF + (size_t)(R + r)*128 + j2*32 + c] = f;
        }
    };
    auto store_z = [&](int q) {
        #pragma unroll
        for (int v = 0; v < 4; ++v) {
            int idx = v*64 + lane;
            int r = idx >> 3, c = (idx & 7) * 4;
            short4v s = *(const short4v*)&S[r*40 + c];
            f32x4 f = { bf2f(s[0]), bf2f(s[1]), bf2f(s[2]), bf2f(s[3]) };
            *(f32x4*)&out[(size_t)(R + r)*64 + q*32 + c] = f;
        }
    };
    auto hpartial = [&](const float* W2, float acc) -> float {
        int rr = lane & 31;
        #pragma unroll
        for (int kk = 0; kk < 32; kk += 8) {
            short8 s = *(const short8*)&S[rr*40 + kk];
            f32x4 w0 = *(const f32x4*)&W2[kk];
            f32x4 w1 = *(const f32x4*)&W2[kk+4];
            acc += bf2f(s[0])*w0[0] + bf2f(s[1])*w0[1] + bf2f(s[2])*w0[2] + bf2f(s[3])*w0[3]
                 + bf2f(s[4])*w1[0] + bf2f(s[5])*w1[1] + bf2f(s[6])*w1[2] + bf2f(s[7])*w1[3];
        }
        return acc;
    };

    // ---- issue superphase-0 staging: fuse + GRU j2-units {0,1} ----
    stage_lds<1664>(ws, &smem[0], t);
    stage_lds<6528>(ws + WS_GRU, &smem[G_BASE], t);

    // ---- A-fragments direct from global (row = R + ln), f32 -> bf16 ----
    short8 fa[5];          // fused input K=80 (z_t 0..63 | emb 64..79)
    short8 ha[8];          // h0 K=128
    {
        const int row = R + ln;
        #pragma unroll
        for (int kf = 0; kf < 4; ++kf) {
            f32x4 p0 = *(const f32x4*)&z_t[(size_t)row*64 + kf*16 + hb8];
            f32x4 p1 = *(const f32x4*)&z_t[(size_t)row*64 + kf*16 + hb8 + 4];
            fa[kf] = packbf(p0, p1);
        }
        int a = action[row];
        f32x4 e0 = *(const f32x4*)&embed[a*16 + hb8];
        f32x4 e1 = *(const f32x4*)&embed[a*16 + hb8 + 4];
        fa[4] = packbf(e0, e1);
        #pragma unroll
        for (int kf = 0; kf < 8; ++kf) {
            f32x4 p0 = *(const f32x4*)&hidden[(size_t)row*128 + kf*16 + hb8];
            f32x4 p1 = *(const f32x4*)&hidden[(size_t)row*128 + kf*16 + hb8 + 4];
            ha[kf] = packbf(p0, p1);
        }
    }
    __syncthreads();                       // B1: fuse + GRU sp0 resident

    // ---- fuse: x = relu(F @ fuse_W^T + b); 4 col-tiles; xa frags from strip ----
    short8 xa[8];
    #pragma unroll
    for (int n = 0; n < 4; ++n) {
        f32x16 a = zz16;
        #pragma unroll
        for (int kf = 0; kf < 5; ++kf) {
            short8 B = *(const short8*)&smem[(n*32 + ln)*104 + kf*16 + hb8];
            a = MFMA32(fa[kf], B, a);
        }
        float fb = fuse_b[n*32 + ln];
        #pragma unroll
        for (int reg = 0; reg < 16; ++reg)
            S[((reg&3) + 8*(reg>>2) + hr4)*40 + ln] = f2bf(fmaxf(a[reg] + fb, 0.f));
        xa[2*n]   = *(const short8*)&S[ln*40 + hb8];
        xa[2*n+1] = *(const short8*)&S[ln*40 + 16 + hb8];
    }

    // ---- GRU superphase 0: j2 = 0,1 ----
    short8 hfa[8];
    GRU_J2(0, 0);
    hfa[0] = *(const short8*)&S[ln*40 + hb8];
    hfa[1] = *(const short8*)&S[ln*40 + 16 + hb8];
    store_hnew(0);
    GRU_J2(1, 1);
    hfa[2] = *(const short8*)&S[ln*40 + hb8];
    hfa[3] = *(const short8*)&S[ln*40 + 16 + hb8];
    store_hnew(1);

    __syncthreads();                       // B2: done reading GRU sp0
    stage_lds<6528>(ws + WS_GRU + 2*WS_GUNIT, &smem[G_BASE], t);
    __syncthreads();                       // B3: sp1 resident

    // ---- GRU superphase 1: j2 = 2,3 ----
    GRU_J2(0, 2);
    hfa[4] = *(const short8*)&S[ln*40 + hb8];
    hfa[5] = *(const short8*)&S[ln*40 + 16 + hb8];
    store_hnew(2);
    GRU_J2(1, 3);
    hfa[6] = *(const short8*)&S[ln*40 + hb8];
    hfa[7] = *(const short8*)&S[ln*40 + 16 + hb8];
    store_hnew(3);

    __syncthreads();                       // B4: done reading GRU sp1
    stage_lds<5440>(ws + WS_HEAD, &smem[G_BASE], t);   // all 10 head units
    __syncthreads();                       // B5: heads resident

    // ---- heads: barrier-free ----
    short8 ta[8];
    HEAD32(hfa, ns_b1[ln],      0, true);
    ta[0] = *(const short8*)&S[ln*40 + hb8];
    ta[1] = *(const short8*)&S[ln*40 + 16 + hb8];
    HEAD32(hfa, ns_b1[32 + ln], 1, true);
    ta[2] = *(const short8*)&S[ln*40 + hb8];
    ta[3] = *(const short8*)&S[ln*40 + 16 + hb8];
    HEAD32(hfa, ns_b1[64 + ln], 2, true);
    ta[4] = *(const short8*)&S[ln*40 + hb8];
    ta[5] = *(const short8*)&S[ln*40 + 16 + hb8];
    HEAD32(hfa, ns_b1[96 + ln], 3, true);
    ta[6] = *(const short8*)&S[ln*40 + hb8];
    ta[7] = *(const short8*)&S[ln*40 + 16 + hb8];

    HEAD32(ta, ns_b2[ln],      4, false); store_z(0);
    HEAD32(ta, ns_b2[32 + ln], 5, false); store_z(1);

    float racc = rw_b2[0];
    HEAD32(hfa, rw_b1[ln],      6, true); racc = hpartial(rw_W2, racc);
    HEAD32(hfa, rw_b1[32 + ln], 7, true); racc = hpartial(rw_W2 + 32, racc);
    if (lane < 32) out[(size_t)BATCH*64 + R + ln] = racc;

    float dacc = dn_b2[0];
    HEAD32(hfa, dn_b1[ln],      8, true); dacc = hpartial(dn_W2, dacc);
    HEAD32(hfa, dn_b1[32 + ln], 9, true); dacc = hpartial(dn_W2 + 32, dacc);
    if (lane < 32) out[(size_t)BATCH*65 + R + ln] = dacc;
}

extern "C" void kernel_launch(void* const* d_in, const int* in_sizes, int n_in,
                              void* d_out, int out_size, void* d_ws, size_t ws_size,
                              hipStream_t stream) {
    const float* z_t    = (const float*)d_in[0];
    const int*   action = (const int*)  d_in[1];
    const float* hidden = (const float*)d_in[2];
    const float* embed  = (const float*)d_in[3];
    const float* fuse_W = (const float*)d_in[4];
    const float* fuse_b = (const float*)d_in[5];
    const float* W_ih   = (const float*)d_in[6];
    const float* W_hh   = (const float*)d_in[7];
    const float* b_ih   = (const float*)d_in[8];
    const float* b_hh   = (const float*)d_in[9];
    const float* ns_W1  = (const float*)d_in[10];
    const float* ns_b1  = (const float*)d_in[11];
    const float* ns_W2  = (const float*)d_in[12];
    const float* ns_b2  = (const float*)d_in[13];
    const float* rw_W1  = (const float*)d_in[14];
    const float* rw_b1  = (const float*)d_in[15];
    const float* rw_W2  = (const float*)d_in[16];
    const float* rw_b2  = (const float*)d_in[17];
    const float* dn_W1  = (const float*)d_in[18];
    const float* dn_b1  = (const float*)d_in[19];
    const float* dn_W2  = (const float*)d_in[20];
    const float* dn_b2  = (const float*)d_in[21];
    float* out = (float*)d_out;
    short* ws  = (short*)d_ws;

    hipLaunchKernelGGL(prep_weights, dim3((WS_ELEMS + 255) / 256), dim3(256), 0, stream,
                       fuse_W, W_ih, W_hh, ns_W1, ns_W2, rw_W1, dn_W1, ws);

    hipLaunchKernelGGL(gru_mfma, dim3(BATCH / 256), dim3(512), 0, stream,
                       z_t, action, hidden, embed,
                       fuse_b, b_ih, b_hh, ns_b1, ns_b2,
                       rw_b1, rw_W2, rw_b2, dn_b1, dn_W2, dn_b2,
                       ws, out);
}